// Round 4
// baseline (851.010 us; speedup 1.0000x reference)
//
#include <hip/hip_runtime.h>
#include <hip/hip_bf16.h>

typedef __bf16 bf16x8 __attribute__((ext_vector_type(8)));
typedef float f32x4 __attribute__((ext_vector_type(4)));

#define NTOT   131072
#define NODES_PER_AUDIO 2048
#define NAUDIO 64
#define POOL_CHUNKS 16
#define CHUNK_NODES (NODES_PER_AUDIO / POOL_CHUNKS)   // 128

// ---------------------------------------------------------------------------
// dtype detection: flag = 1 -> bf16 inputs ; flag = 0 -> f32 inputs
// ---------------------------------------------------------------------------
__global__ __launch_bounds__(256)
void detect_dtype(const unsigned* __restrict__ x, int* __restrict__ flag)
{
    const int tid = threadIdx.x;
    int cnt = 0;
    for (int i = tid; i < 4096; i += 256) {
        unsigned e = (x[i] >> 7) & 0xFF;
        cnt += (e >= 100 && e <= 145) ? 1 : 0;
    }
    __shared__ int red[256];
    red[tid] = cnt; __syncthreads();
    for (int s = 128; s > 0; s >>= 1) {
        if (tid < s) red[tid] += red[tid + s];
        __syncthreads();
    }
    if (tid == 0) *flag = (red[0] > 3000) ? 1 : 0;
}

struct W14 { const void* s[14]; int n[14]; int off[14]; };

__global__ __launch_bounds__(256)
void convert_weights(W14 w, const int* __restrict__ flag, __bf16* __restrict__ wb)
{
    const int f = *flag;
    const int stride = gridDim.x * 256;
    for (int t = 0; t < 14; t++) {
        const void* src = w.s[t];
        __bf16* d = wb + w.off[t];
        for (int i = blockIdx.x * 256 + threadIdx.x; i < w.n[t]; i += stride)
            d[i] = f ? ((const __bf16*)src)[i] : (__bf16)((const float*)src)[i];
    }
}

// ---------------------------------------------------------------------------
// Reg-staged double-buffered GEMM: C[M,Nc] = A[M,K] @ W[Nc,K]^T.
// 128x128 tile, 4 waves (2x2 of 64x64), BK=64, mfma_f32_16x16x32_bf16.
// Pipeline (plain HIP, no asm): per K-step issue next tile's global->reg
// loads, ds_read frags + 32 MFMA on current buffer (load latency hides
// under MFMA), ds_write regs -> other buffer, ONE __syncthreads per step.
// LDS chunk-XOR swizzle: slot s of row r holds global chunk s^(r&7);
// writes land linear (thread's chunk c -> addr c*16B), reads XOR the slot
// -> conflict-free ds_read_b128 (row-major [r][64] would be 16-way).
// XCD-aware block swizzle as round 0 (y-stripe per XCD, col tiles adjacent).
// DYN: A dtype by flag (bf16 direct, or f32 load+cvt during reg-stage).
// ---------------------------------------------------------------------------
template<int NX, bool DYN>
__global__ __launch_bounds__(256)
void gemm_rs(const void* __restrict__ Araw, const __bf16* __restrict__ W,
             __bf16* __restrict__ C, int M, int K, int Nc,
             const int* __restrict__ flagp)
{
    __shared__ __align__(16) __bf16 As[2 * 128 * 64];
    __shared__ __align__(16) __bf16 Bs[2 * 128 * 64];

    // XCD swizzle: xcd = bid&7 owns contiguous y-stripe of row tiles
    const int nb  = gridDim.x;
    const int ny  = nb / NX;
    const int ypx = ny >> 3;
    const int bid = blockIdx.x;
    const int xcd = bid & 7;
    const int local = bid >> 3;
    const int by = xcd * ypx + local / NX;
    const int bx = local % NX;
    const int rowBase = by * 128, colBase = bx * 128;

    const int tid  = threadIdx.x;
    const int wave = tid >> 6, lane = tid & 63;
    const int wrow = (wave >> 1) * 64, wcol = (wave & 1) * 64;
    const int lr = lane & 15, lq = lane >> 4;
    int f = 1;
    if constexpr (DYN) f = *flagp;

    const __bf16* A16 = (const __bf16*)Araw;
    const float*  A32 = (const float*)Araw;

    // staging: thread owns chunks c = tid + 256*i (16 B each), i<4.
    // row r = c>>3, slot = c&7, fetched global chunk q = slot^(r&7);
    // LDS write slot = q^(r&7) = slot -> linear dest c*8 elements.
    const __bf16* apB[4]; const float* apF[4]; const __bf16* bpB[4]; int ld[4];
    #pragma unroll
    for (int i = 0; i < 4; i++) {
        const int c = tid + 256 * i, r = c >> 3, q = (c & 7) ^ (r & 7);
        apB[i] = A16 + (size_t)(rowBase + r) * K + q * 8;
        apF[i] = A32 + (size_t)(rowBase + r) * K + q * 8;
        bpB[i] = W   + (size_t)(colBase + r) * K + q * 8;
        ld[i]  = c * 8;
    }

    f32x4 acc[4][4] = {};
    const int NS = K >> 6;
    int4 sa[4], sb[4];

    // ---- reg-stage load of K-step S ----
    #define LOADR(S) do {                                                     \
        const int _k0 = (S) * 64;                                             \
        _Pragma("unroll")                                                     \
        for (int _i = 0; _i < 4; _i++) {                                      \
            if (!DYN || f) {                                                  \
                sa[_i] = *(const int4*)(apB[_i] + _k0);                       \
            } else {                                                          \
                float4 u0 = *(const float4*)(apF[_i] + _k0);                  \
                float4 u1 = *(const float4*)(apF[_i] + _k0 + 4);              \
                __bf16 t[8] = {(__bf16)u0.x, (__bf16)u0.y, (__bf16)u0.z,      \
                               (__bf16)u0.w, (__bf16)u1.x, (__bf16)u1.y,      \
                               (__bf16)u1.z, (__bf16)u1.w};                   \
                sa[_i] = *(const int4*)t;                                     \
            }                                                                 \
            sb[_i] = *(const int4*)(bpB[_i] + _k0);                           \
        } } while (0)

    #define WRITER(P) do {                                                    \
        _Pragma("unroll")                                                     \
        for (int _i = 0; _i < 4; _i++) {                                      \
            *(int4*)&As[(P) * 8192 + ld[_i]] = sa[_i];                        \
            *(int4*)&Bs[(P) * 8192 + ld[_i]] = sb[_i];                        \
        } } while (0)

    // prologue: tile 0 -> regs -> buf 0
    LOADR(0);
    WRITER(0);
    __syncthreads();

    for (int s = 0; s < NS; ++s) {
        const int p = s & 1;
        if (s + 1 < NS) LOADR(s + 1);   // issue early; waited only at WRITER

        #pragma unroll
        for (int kk = 0; kk < 2; kk++) {
            bf16x8 av[4], bv[4];
            #pragma unroll
            for (int i = 0; i < 4; i++) {
                const int ra = wrow + i * 16 + lr;
                av[i] = *(const bf16x8*)
                    &As[p * 8192 + ra * 64 + (((kk * 4 + lq) ^ (ra & 7)) * 8)];
                const int rb = wcol + i * 16 + lr;
                bv[i] = *(const bf16x8*)
                    &Bs[p * 8192 + rb * 64 + (((kk * 4 + lq) ^ (rb & 7)) * 8)];
            }
            #pragma unroll
            for (int i = 0; i < 4; i++)
                #pragma unroll
                for (int j = 0; j < 4; j++)
                    acc[i][j] = __builtin_amdgcn_mfma_f32_16x16x32_bf16(
                        av[i], bv[j], acc[i][j], 0, 0, 0);
        }

        if (s + 1 < NS) WRITER(p ^ 1);  // fill other buffer (post-MFMA wait)
        __syncthreads();
    }
    #undef LOADR
    #undef WRITER

    #pragma unroll
    for (int i = 0; i < 4; i++) {
        #pragma unroll
        for (int j = 0; j < 4; j++) {
            int col = colBase + wcol + j * 16 + lr;
            #pragma unroll
            for (int r = 0; r < 4; r++) {
                int row = rowBase + wrow + i * 16 + lq * 4 + r;
                C[(size_t)row * Nc + col] = (__bf16)acc[i][j][r];
            }
        }
    }
}

// ---------------------------------------------------------------------------
// Fused GAT edge-softmax + aggregation (+ optional node head).
// One wave per node n. In-edges = {self, n-1 if same audio}.
// ---------------------------------------------------------------------------
template<int C, bool RELU, bool FUSE_HEAD>
__global__ __launch_bounds__(256)
void agg_fused(const __bf16* __restrict__ h, const __bf16* __restrict__ a_s,
               const __bf16* __restrict__ a_d, const __bf16* __restrict__ bias,
               void* __restrict__ outv,
               const __bf16* __restrict__ Wn, const __bf16* __restrict__ bn,
               const __bf16* __restrict__ Wt, const __bf16* __restrict__ bt,
               void* __restrict__ node_pred, float* __restrict__ logit,
               const int* __restrict__ flag)
{
    constexpr int D = 2 * C;
    constexpr int V = D / 64;
    const int n = blockIdx.x * 4 + (threadIdx.x >> 6);
    const int lane = threadIdx.x & 63;
    const bool have_prev = (n & (NODES_PER_AUDIO - 1)) != 0;
    const size_t np = have_prev ? (size_t)(n - 1) : (size_t)n;
    const int base = lane * V;

    __bf16 h0v[V], h1v[V], asv[V], adv[V];
    if constexpr (V == 8) {
        *(int4*)h0v = *(const int4*)(h + (size_t)n * D + base);
        *(int4*)h1v = *(const int4*)(h + np * D + base);
        *(int4*)asv = *(const int4*)(a_s + base);
        *(int4*)adv = *(const int4*)(a_d + base);
    } else {
        *(int2*)h0v = *(const int2*)(h + (size_t)n * D + base);
        *(int2*)h1v = *(const int2*)(h + np * D + base);
        *(int2*)asv = *(const int2*)(a_s + base);
        *(int2*)adv = *(const int2*)(a_d + base);
    }

    float ps = 0.f, pd = 0.f, pp = 0.f;
    #pragma unroll
    for (int j = 0; j < V; j++) {
        float av = (float)asv[j], dv = (float)adv[j];
        float x0 = (float)h0v[j], x1 = (float)h1v[j];
        ps += x0 * av; pd += x0 * dv; pp += x1 * av;
    }
    #pragma unroll
    for (int off = 1; off < 32; off <<= 1) {
        ps += __shfl_xor(ps, off, 64);
        pd += __shfl_xor(pd, off, 64);
        pp += __shfl_xor(pp, off, 64);
    }

    float es = ps + pd;  es = es > 0.f ? es : 0.2f * es;
    float a_self = 1.f, a_prev = 0.f;
    if (have_prev) {
        float ep = pp + pd;  ep = ep > 0.f ? ep : 0.2f * ep;
        float m = fmaxf(es, ep);
        float wsx = __expf(es - m), wpx = __expf(ep - m);
        float inv = 1.f / (wsx + wpx);
        a_self = wsx * inv; a_prev = wpx * inv;
    }

    const int cb = (lane & 31) * V;
    float outj[V];
    #pragma unroll
    for (int j = 0; j < V; j++) {
        float p = a_self * (float)h0v[j] + a_prev * (float)h1v[j];
        p = 0.5f * (p + __shfl_xor(p, 32, 64));
        p += (float)bias[cb + j];
        if (RELU) p = fmaxf(p, 0.f);
        outj[j] = p;
    }

    if constexpr (!FUSE_HEAD) {
        if (lane < 32) {
            __bf16 ov[V];
            #pragma unroll
            for (int j = 0; j < V; j++) ov[j] = (__bf16)outj[j];
            if constexpr (V == 8)
                *(int4*)((__bf16*)outv + (size_t)n * C + cb) = *(int4*)ov;
            else
                *(int2*)((__bf16*)outv + (size_t)n * C + cb) = *(int2*)ov;
        }
    } else {
        if (lane < 32)
            *(float4*)((float*)outv + (size_t)n * C + cb) = *(float4*)outj;

        float acc[8];
        #pragma unroll
        for (int k = 0; k < 7; k++) {
            float a = 0.f;
            #pragma unroll
            for (int j = 0; j < V; j++)
                a += outj[j] * (float)Wn[k * C + cb + j];
            acc[k] = a;
        }
        {
            float a = 0.f;
            #pragma unroll
            for (int j = 0; j < V; j++)
                a += outj[j] * (float)Wt[cb + j];
            acc[7] = a;
        }
        #pragma unroll
        for (int off = 1; off < 32; off <<= 1)
            #pragma unroll
            for (int k = 0; k < 8; k++)
                acc[k] += __shfl_xor(acc[k], off, 64);

        if (lane == 0) {
            float lg[7], m = -1e30f;
            #pragma unroll
            for (int k = 0; k < 7; k++) {
                lg[k] = acc[k] + (float)bn[k];
                m = fmaxf(m, lg[k]);
            }
            float s = 0.f;
            #pragma unroll
            for (int k = 0; k < 7; k++) { lg[k] = __expf(lg[k] - m); s += lg[k]; }
            float inv = 1.f / s;
            if (*flag) {
                #pragma unroll
                for (int k = 0; k < 7; k++)
                    ((__bf16*)node_pred)[(size_t)n * 7 + k] = (__bf16)(lg[k] * inv);
            } else {
                #pragma unroll
                for (int k = 0; k < 7; k++)
                    ((float*)node_pred)[(size_t)n * 7 + k] = lg[k] * inv;
            }
            logit[n] = acc[7] + (float)bt[0];
        }
    }
}

// ---------------------------------------------------------------------------
__global__ __launch_bounds__(256)
void audio_stats(const float* __restrict__ logit, float2* __restrict__ stats)
{
    const int b = blockIdx.x;
    const int tid = threadIdx.x;
    __shared__ float red[256];
    const float* lg = logit + b * NODES_PER_AUDIO;

    float m = -1e30f;
    for (int i = tid; i < NODES_PER_AUDIO; i += 256) m = fmaxf(m, lg[i]);
    red[tid] = m; __syncthreads();
    for (int s = 128; s > 0; s >>= 1) {
        if (tid < s) red[tid] = fmaxf(red[tid], red[tid + s]);
        __syncthreads();
    }
    m = red[0]; __syncthreads();

    float s = 0.f;
    for (int i = tid; i < NODES_PER_AUDIO; i += 256) s += __expf(lg[i] - m);
    red[tid] = s; __syncthreads();
    for (int st = 128; st > 0; st >>= 1) {
        if (tid < st) red[tid] += red[tid + st];
        __syncthreads();
    }
    if (tid == 0) stats[b] = make_float2(m, 1.f / red[0]);
}

__global__ __launch_bounds__(256)
void audio_partial(const float* __restrict__ emb, const float* __restrict__ logit,
                   const float2* __restrict__ stats, float* __restrict__ partial)
{
    const int b = blockIdx.x >> 4;
    const int chunk = blockIdx.x & 15;
    const int tid = threadIdx.x;
    const int c = tid & 127, half = tid >> 7;
    const float m = stats[b].x, inv = stats[b].y;
    const float* lg = logit + b * NODES_PER_AUDIO;
    const float* eb = emb + (size_t)b * NODES_PER_AUDIO * 128;

    __shared__ float attbuf[256];
    const int n0 = chunk * CHUNK_NODES + half * (CHUNK_NODES / 2);
    float att = 0.f;
    for (int i = n0; i < n0 + CHUNK_NODES / 2; i++) {
        float w = __expf(lg[i] - m) * inv;
        att += w * eb[(size_t)i * 128 + c];
    }
    attbuf[tid] = att; __syncthreads();
    if (tid < 128)
        partial[(size_t)(b * POOL_CHUNKS + chunk) * 128 + tid] =
            attbuf[tid] + attbuf[tid + 128];
}

__global__ __launch_bounds__(64)
void audio_final(const float* __restrict__ partial, const __bf16* __restrict__ Wa,
                 const __bf16* __restrict__ ba, void* __restrict__ outbase,
                 const int* __restrict__ flag)
{
    const int b = blockIdx.x;
    const int lane = threadIdx.x;
    const float* pb = partial + (size_t)b * POOL_CHUNKS * 128;

    float a0 = 0.f, a1 = 0.f;
    #pragma unroll
    for (int k = 0; k < POOL_CHUNKS; k++) {
        a0 += pb[k * 128 + lane * 2];
        a1 += pb[k * 128 + lane * 2 + 1];
    }
    float p0 = a0 * (float)Wa[lane * 2]       + a1 * (float)Wa[lane * 2 + 1];
    float p1 = a0 * (float)Wa[128 + lane * 2] + a1 * (float)Wa[128 + lane * 2 + 1];
    #pragma unroll
    for (int off = 1; off < 64; off <<= 1) {
        p0 += __shfl_xor(p0, off, 64);
        p1 += __shfl_xor(p1, off, 64);
    }
    if (lane == 0) {
        float r0 = p0 + (float)ba[0];
        float r1 = p1 + (float)ba[1];
        if (*flag) {
            ((__bf16*)outbase)[(size_t)NTOT * 7 + b * 2 + 0] = (__bf16)r0;
            ((__bf16*)outbase)[(size_t)NTOT * 7 + b * 2 + 1] = (__bf16)r1;
        } else {
            ((float*)outbase)[(size_t)NTOT * 7 + b * 2 + 0] = r0;
            ((float*)outbase)[(size_t)NTOT * 7 + b * 2 + 1] = r1;
        }
    }
}

// ---------------------------------------------------------------------------
extern "C" void kernel_launch(void* const* d_in, const int* in_sizes, int n_in,
                              void* d_out, int out_size, void* d_ws, size_t ws_size,
                              hipStream_t stream)
{
    const void* x = d_in[0];
    char* ws = (char*)d_ws;
    const size_t N = NTOT;

    __bf16* h  = (__bf16*)ws;
    size_t off = N * 1024;
    __bf16* h1 = (__bf16*)(ws + off); off += N * 512;
    float* logit = (float*)(ws + off); off += N * 4;
    __bf16* wb = (__bf16*)(ws + off); off += 331008 * 2;
    int* flag = (int*)(ws + off); off += 16;
    float2* stats = (float2*)(ws + off); off += NAUDIO * sizeof(float2);
    float* partial = (float*)(ws + off); off += (size_t)NAUDIO * POOL_CHUNKS * 128 * 4;
    __bf16* g2 = h;                        // aliases dead h
    float* emb = (float*)(ws + N * 512);   // aliases dead h (2nd half)

    const int O_W1 = 0,      O_W2 = 262144, O_as1 = 327680, O_ad1 = 328192;
    const int O_b1 = 328704, O_as2 = 328960, O_ad2 = 329216, O_b2 = 329472;
    const int O_Wt = 329600, O_bt = 329728, O_Wa = 329736, O_ba = 329992;
    const int O_Wn = 330000, O_bn = 330896;

    W14 w;
    const void* srcs[14] = { d_in[4], d_in[8], d_in[5], d_in[6], d_in[7],
                             d_in[9], d_in[10], d_in[11], d_in[12], d_in[13],
                             d_in[14], d_in[15], d_in[16], d_in[17] };
    const int ns[14]   = { 262144, 65536, 512, 512, 256, 256, 256, 128,
                           128, 1, 256, 2, 896, 7 };
    const int offs[14] = { O_W1, O_W2, O_as1, O_ad1, O_b1, O_as2, O_ad2, O_b2,
                           O_Wt, O_bt, O_Wa, O_ba, O_Wn, O_bn };
    for (int i = 0; i < 14; i++) { w.s[i] = srcs[i]; w.n[i] = ns[i]; w.off[i] = offs[i]; }

    const int nwb = NTOT / 4;

    detect_dtype<<<1, 256, 0, stream>>>((const unsigned*)x, flag);
    convert_weights<<<512, 256, 0, stream>>>(w, flag, wb);

    // 1) h = x @ W1^T  (f32->bf16 conversion fused into reg staging)
    gemm_rs<4, true><<<4 * (NTOT / 128), 256, 0, stream>>>(
        x, wb + O_W1, h, NTOT, 512, 512, flag);
    // 2) fused GAT layer 1: edge softmax + aggregate + relu -> h1
    agg_fused<256, true, false><<<nwb, 256, 0, stream>>>(
        h, wb + O_as1, wb + O_ad1, wb + O_b1, h1,
        nullptr, nullptr, nullptr, nullptr, nullptr, nullptr, flag);
    // 3) g2 = h1 @ W2^T
    gemm_rs<2, false><<<2 * (NTOT / 128), 256, 0, stream>>>(
        h1, wb + O_W2, g2, NTOT, 256, 256, flag);
    // 4) fused GAT layer 2 + node head: emb (f32) + node_pred + logit
    agg_fused<128, false, true><<<nwb, 256, 0, stream>>>(
        g2, wb + O_as2, wb + O_ad2, wb + O_b2, emb,
        wb + O_Wn, wb + O_bn, wb + O_Wt, wb + O_bt, d_out, logit, flag);
    // 5) per-audio softmax pool + audio head
    audio_stats<<<NAUDIO, 256, 0, stream>>>(logit, stats);
    audio_partial<<<NAUDIO * POOL_CHUNKS, 256, 0, stream>>>(emb, logit, stats, partial);
    audio_final<<<NAUDIO, 64, 0, stream>>>(partial, wb + O_Wa, wb + O_ba, d_out, flag);
}

// Round 5
// 707.637 us; speedup vs baseline: 1.2026x; 1.2026x over previous
//
#include <hip/hip_runtime.h>
#include <hip/hip_bf16.h>

typedef __bf16 bf16x8 __attribute__((ext_vector_type(8)));
typedef float f32x4 __attribute__((ext_vector_type(4)));

#define NTOT   131072
#define NODES_PER_AUDIO 2048
#define NAUDIO 64
#define POOL_CHUNKS 16
#define CHUNK_NODES (NODES_PER_AUDIO / POOL_CHUNKS)   // 128

// ---------------------------------------------------------------------------
// dtype detection: flag = 1 -> bf16 inputs ; flag = 0 -> f32 inputs
// ---------------------------------------------------------------------------
__global__ __launch_bounds__(256)
void detect_dtype(const unsigned* __restrict__ x, int* __restrict__ flag)
{
    const int tid = threadIdx.x;
    int cnt = 0;
    for (int i = tid; i < 4096; i += 256) {
        unsigned e = (x[i] >> 7) & 0xFF;
        cnt += (e >= 100 && e <= 145) ? 1 : 0;
    }
    __shared__ int red[256];
    red[tid] = cnt; __syncthreads();
    for (int s = 128; s > 0; s >>= 1) {
        if (tid < s) red[tid] += red[tid + s];
        __syncthreads();
    }
    if (tid == 0) *flag = (red[0] > 3000) ? 1 : 0;
}

struct W14 { const void* s[14]; int n[14]; int off[14]; };

__global__ __launch_bounds__(256)
void convert_weights(W14 w, const int* __restrict__ flag, __bf16* __restrict__ wb)
{
    const int f = *flag;
    const int stride = gridDim.x * 256;
    for (int t = 0; t < 14; t++) {
        const void* src = w.s[t];
        __bf16* d = wb + w.off[t];
        for (int i = blockIdx.x * 256 + threadIdx.x; i < w.n[t]; i += stride)
            d[i] = f ? ((const __bf16*)src)[i] : (__bf16)((const float*)src)[i];
    }
}

// ---------------------------------------------------------------------------
// GEMM: C[M,Nc] = A[M,K] @ W[Nc,K]^T (fp32 accum), 128x128 tile, BK=64,
// 4 waves (2x2 of 64x64), mfma_f32_16x16x32_bf16. Round-0 structure
// (global_load_lds staging, single buffer, 2 barriers/K-step, XCD swizzle)
// with ONE change: FRAGMENT-MAJOR LDS layout.
//   LDS chunk c (16B) = group g = c>>6 (= rowblock ib = g>>1, khalf kk = g&1),
//   lane l = c&63  ->  holds  row ib*16+(l&15), cols kk*32+(l>>4)*8 .. +8.
//   Staging: per-lane pre-permuted GLOBAL source, linear LDS dest (as
//   global_load_lds requires). Same-line merging keeps 16 lines/wave-issue,
//   so HBM coalescing is unchanged vs row-major.
//   Fragment reads become base + lane*16B  ->  lane-contiguous ds_read_b128
//   (the m134-proven conflict-free pattern; row-major was 16-way).
// DYN: A dtype by flag (1=bf16 via global_load_lds, 0=f32 load+cvt+ds_write).
// ---------------------------------------------------------------------------
template<int NX, bool DYN>
__global__ __launch_bounds__(256)
void gemm_tile(const void* __restrict__ Araw, const __bf16* __restrict__ W,
               __bf16* __restrict__ C, int M, int K, int Nc,
               const int* __restrict__ flagp)
{
    __shared__ __align__(16) __bf16 As[128 * 64];
    __shared__ __align__(16) __bf16 Bs[128 * 64];

    // swizzle: xcd = bid&7 owns y-stripe [xcd*ypx, +ypx)
    const int nb  = gridDim.x;
    const int ny  = nb / NX;
    const int ypx = ny >> 3;                 // y tiles per XCD
    const int bid = blockIdx.x;
    const int xcd = bid & 7;
    const int local = bid >> 3;
    const int by = xcd * ypx + local / NX;
    const int bx = local % NX;

    const int colBase = bx * 128;
    const int rowBase = by * 128;
    const int tid  = threadIdx.x;
    const int wave = tid >> 6;
    const int lane = tid & 63;
    const int wrow = (wave >> 1) * 64;
    const int wcol = (wave & 1) * 64;
    const int lr = lane & 15;
    const int lq = lane >> 4;
    int f = 1;
    if constexpr (DYN) f = *flagp;

    f32x4 acc[4][4] = {};

    // 1024 16B chunks per matrix per K-step; 4 per thread (c = tid + 256*i).
    // fragment-major: g=c>>6, l=c&63 -> row=(g>>1)*16+(l&15), slot=(g&1)*4+(l>>4)
    const __bf16* A16 = (const __bf16*)Araw;
    const float*  A32 = (const float*)Araw;
    const __bf16* ap[4]; const float* af32[4]; const __bf16* bp[4];
    #pragma unroll
    for (int i = 0; i < 4; i++) {
        const int c = tid + 256 * i;
        const int g = c >> 6, l = c & 63;
        const int r = (g >> 1) * 16 + (l & 15);
        const int q = (g & 1) * 4 + (l >> 4);
        ap[i]   = A16 + (size_t)(rowBase + r) * K + q * 8;
        af32[i] = A32 + (size_t)(rowBase + r) * K + q * 8;
        bp[i]   = W   + (size_t)(colBase + r) * K + q * 8;
    }

    for (int k0 = 0; k0 < K; k0 += 64) {
        __syncthreads();
        #pragma unroll
        for (int i = 0; i < 4; i++) {
            const int c = tid + 256 * i;
            __builtin_amdgcn_global_load_lds(
                (const __attribute__((address_space(1))) void*)(bp[i] + k0),
                (__attribute__((address_space(3))) void*)&Bs[c * 8], 16, 0, 0);
        }
        if (!DYN || f) {
            #pragma unroll
            for (int i = 0; i < 4; i++) {
                const int c = tid + 256 * i;
                __builtin_amdgcn_global_load_lds(
                    (const __attribute__((address_space(1))) void*)(ap[i] + k0),
                    (__attribute__((address_space(3))) void*)&As[c * 8], 16, 0, 0);
            }
        } else {
            #pragma unroll
            for (int i = 0; i < 4; i++) {
                const int c = tid + 256 * i;
                float4 u0 = *(const float4*)(af32[i] + k0);
                float4 u1 = *(const float4*)(af32[i] + k0 + 4);
                __bf16 t[8] = {(__bf16)u0.x, (__bf16)u0.y, (__bf16)u0.z, (__bf16)u0.w,
                               (__bf16)u1.x, (__bf16)u1.y, (__bf16)u1.z, (__bf16)u1.w};
                *(int4*)&As[c * 8] = *(int4*)t;
            }
        }
        __syncthreads();

        #pragma unroll
        for (int kk = 0; kk < 2; kk++) {
            bf16x8 avf[4], bvf[4];
            #pragma unroll
            for (int i = 0; i < 4; i++)
                avf[i] = *(const bf16x8*)
                    &As[(((((wrow >> 4) + i) * 2) + kk) * 64 + lane) * 8];
            #pragma unroll
            for (int j = 0; j < 4; j++)
                bvf[j] = *(const bf16x8*)
                    &Bs[(((((wcol >> 4) + j) * 2) + kk) * 64 + lane) * 8];
            #pragma unroll
            for (int i = 0; i < 4; i++)
                #pragma unroll
                for (int j = 0; j < 4; j++)
                    acc[i][j] = __builtin_amdgcn_mfma_f32_16x16x32_bf16(
                        avf[i], bvf[j], acc[i][j], 0, 0, 0);
        }
    }

    #pragma unroll
    for (int i = 0; i < 4; i++) {
        #pragma unroll
        for (int j = 0; j < 4; j++) {
            int col = colBase + wcol + j * 16 + lr;
            #pragma unroll
            for (int r = 0; r < 4; r++) {
                int row = rowBase + wrow + i * 16 + lq * 4 + r;
                C[(size_t)row * Nc + col] = (__bf16)acc[i][j][r];
            }
        }
    }
}

// ---------------------------------------------------------------------------
// Fused GAT edge-softmax + aggregation (+ optional node head).
// One wave per node n. In-edges = {self, n-1 if same audio}.
// ---------------------------------------------------------------------------
template<int C, bool RELU, bool FUSE_HEAD>
__global__ __launch_bounds__(256)
void agg_fused(const __bf16* __restrict__ h, const __bf16* __restrict__ a_s,
               const __bf16* __restrict__ a_d, const __bf16* __restrict__ bias,
               void* __restrict__ outv,
               const __bf16* __restrict__ Wn, const __bf16* __restrict__ bn,
               const __bf16* __restrict__ Wt, const __bf16* __restrict__ bt,
               void* __restrict__ node_pred, float* __restrict__ logit,
               const int* __restrict__ flag)
{
    constexpr int D = 2 * C;
    constexpr int V = D / 64;
    const int n = blockIdx.x * 4 + (threadIdx.x >> 6);
    const int lane = threadIdx.x & 63;
    const bool have_prev = (n & (NODES_PER_AUDIO - 1)) != 0;
    const size_t np = have_prev ? (size_t)(n - 1) : (size_t)n;
    const int base = lane * V;

    __bf16 h0v[V], h1v[V], asv[V], adv[V];
    if constexpr (V == 8) {
        *(int4*)h0v = *(const int4*)(h + (size_t)n * D + base);
        *(int4*)h1v = *(const int4*)(h + np * D + base);
        *(int4*)asv = *(const int4*)(a_s + base);
        *(int4*)adv = *(const int4*)(a_d + base);
    } else {
        *(int2*)h0v = *(const int2*)(h + (size_t)n * D + base);
        *(int2*)h1v = *(const int2*)(h + np * D + base);
        *(int2*)asv = *(const int2*)(a_s + base);
        *(int2*)adv = *(const int2*)(a_d + base);
    }

    float ps = 0.f, pd = 0.f, pp = 0.f;
    #pragma unroll
    for (int j = 0; j < V; j++) {
        float av = (float)asv[j], dv = (float)adv[j];
        float x0 = (float)h0v[j], x1 = (float)h1v[j];
        ps += x0 * av; pd += x0 * dv; pp += x1 * av;
    }
    #pragma unroll
    for (int off = 1; off < 32; off <<= 1) {
        ps += __shfl_xor(ps, off, 64);
        pd += __shfl_xor(pd, off, 64);
        pp += __shfl_xor(pp, off, 64);
    }

    float es = ps + pd;  es = es > 0.f ? es : 0.2f * es;
    float a_self = 1.f, a_prev = 0.f;
    if (have_prev) {
        float ep = pp + pd;  ep = ep > 0.f ? ep : 0.2f * ep;
        float m = fmaxf(es, ep);
        float wsx = __expf(es - m), wpx = __expf(ep - m);
        float inv = 1.f / (wsx + wpx);
        a_self = wsx * inv; a_prev = wpx * inv;
    }

    const int cb = (lane & 31) * V;
    float outj[V];
    #pragma unroll
    for (int j = 0; j < V; j++) {
        float p = a_self * (float)h0v[j] + a_prev * (float)h1v[j];
        p = 0.5f * (p + __shfl_xor(p, 32, 64));
        p += (float)bias[cb + j];
        if (RELU) p = fmaxf(p, 0.f);
        outj[j] = p;
    }

    if constexpr (!FUSE_HEAD) {
        if (lane < 32) {
            __bf16 ov[V];
            #pragma unroll
            for (int j = 0; j < V; j++) ov[j] = (__bf16)outj[j];
            if constexpr (V == 8)
                *(int4*)((__bf16*)outv + (size_t)n * C + cb) = *(int4*)ov;
            else
                *(int2*)((__bf16*)outv + (size_t)n * C + cb) = *(int2*)ov;
        }
    } else {
        if (lane < 32)
            *(float4*)((float*)outv + (size_t)n * C + cb) = *(float4*)outj;

        float acc[8];
        #pragma unroll
        for (int k = 0; k < 7; k++) {
            float a = 0.f;
            #pragma unroll
            for (int j = 0; j < V; j++)
                a += outj[j] * (float)Wn[k * C + cb + j];
            acc[k] = a;
        }
        {
            float a = 0.f;
            #pragma unroll
            for (int j = 0; j < V; j++)
                a += outj[j] * (float)Wt[cb + j];
            acc[7] = a;
        }
        #pragma unroll
        for (int off = 1; off < 32; off <<= 1)
            #pragma unroll
            for (int k = 0; k < 8; k++)
                acc[k] += __shfl_xor(acc[k], off, 64);

        if (lane == 0) {
            float lg[7], m = -1e30f;
            #pragma unroll
            for (int k = 0; k < 7; k++) {
                lg[k] = acc[k] + (float)bn[k];
                m = fmaxf(m, lg[k]);
            }
            float s = 0.f;
            #pragma unroll
            for (int k = 0; k < 7; k++) { lg[k] = __expf(lg[k] - m); s += lg[k]; }
            float inv = 1.f / s;
            if (*flag) {
                #pragma unroll
                for (int k = 0; k < 7; k++)
                    ((__bf16*)node_pred)[(size_t)n * 7 + k] = (__bf16)(lg[k] * inv);
            } else {
                #pragma unroll
                for (int k = 0; k < 7; k++)
                    ((float*)node_pred)[(size_t)n * 7 + k] = lg[k] * inv;
            }
            logit[n] = acc[7] + (float)bt[0];
        }
    }
}

// ---------------------------------------------------------------------------
__global__ __launch_bounds__(256)
void audio_stats(const float* __restrict__ logit, float2* __restrict__ stats)
{
    const int b = blockIdx.x;
    const int tid = threadIdx.x;
    __shared__ float red[256];
    const float* lg = logit + b * NODES_PER_AUDIO;

    float m = -1e30f;
    for (int i = tid; i < NODES_PER_AUDIO; i += 256) m = fmaxf(m, lg[i]);
    red[tid] = m; __syncthreads();
    for (int s = 128; s > 0; s >>= 1) {
        if (tid < s) red[tid] = fmaxf(red[tid], red[tid + s]);
        __syncthreads();
    }
    m = red[0]; __syncthreads();

    float s = 0.f;
    for (int i = tid; i < NODES_PER_AUDIO; i += 256) s += __expf(lg[i] - m);
    red[tid] = s; __syncthreads();
    for (int st = 128; st > 0; st >>= 1) {
        if (tid < st) red[tid] += red[tid + st];
        __syncthreads();
    }
    if (tid == 0) stats[b] = make_float2(m, 1.f / red[0]);
}

__global__ __launch_bounds__(256)
void audio_partial(const float* __restrict__ emb, const float* __restrict__ logit,
                   const float2* __restrict__ stats, float* __restrict__ partial)
{
    const int b = blockIdx.x >> 4;
    const int chunk = blockIdx.x & 15;
    const int tid = threadIdx.x;
    const int c = tid & 127, half = tid >> 7;
    const float m = stats[b].x, inv = stats[b].y;
    const float* lg = logit + b * NODES_PER_AUDIO;
    const float* eb = emb + (size_t)b * NODES_PER_AUDIO * 128;

    __shared__ float attbuf[256];
    const int n0 = chunk * CHUNK_NODES + half * (CHUNK_NODES / 2);
    float att = 0.f;
    for (int i = n0; i < n0 + CHUNK_NODES / 2; i++) {
        float w = __expf(lg[i] - m) * inv;
        att += w * eb[(size_t)i * 128 + c];
    }
    attbuf[tid] = att; __syncthreads();
    if (tid < 128)
        partial[(size_t)(b * POOL_CHUNKS + chunk) * 128 + tid] =
            attbuf[tid] + attbuf[tid + 128];
}

__global__ __launch_bounds__(64)
void audio_final(const float* __restrict__ partial, const __bf16* __restrict__ Wa,
                 const __bf16* __restrict__ ba, void* __restrict__ outbase,
                 const int* __restrict__ flag)
{
    const int b = blockIdx.x;
    const int lane = threadIdx.x;
    const float* pb = partial + (size_t)b * POOL_CHUNKS * 128;

    float a0 = 0.f, a1 = 0.f;
    #pragma unroll
    for (int k = 0; k < POOL_CHUNKS; k++) {
        a0 += pb[k * 128 + lane * 2];
        a1 += pb[k * 128 + lane * 2 + 1];
    }
    float p0 = a0 * (float)Wa[lane * 2]       + a1 * (float)Wa[lane * 2 + 1];
    float p1 = a0 * (float)Wa[128 + lane * 2] + a1 * (float)Wa[128 + lane * 2 + 1];
    #pragma unroll
    for (int off = 1; off < 64; off <<= 1) {
        p0 += __shfl_xor(p0, off, 64);
        p1 += __shfl_xor(p1, off, 64);
    }
    if (lane == 0) {
        float r0 = p0 + (float)ba[0];
        float r1 = p1 + (float)ba[1];
        if (*flag) {
            ((__bf16*)outbase)[(size_t)NTOT * 7 + b * 2 + 0] = (__bf16)r0;
            ((__bf16*)outbase)[(size_t)NTOT * 7 + b * 2 + 1] = (__bf16)r1;
        } else {
            ((float*)outbase)[(size_t)NTOT * 7 + b * 2 + 0] = r0;
            ((float*)outbase)[(size_t)NTOT * 7 + b * 2 + 1] = r1;
        }
    }
}

// ---------------------------------------------------------------------------
extern "C" void kernel_launch(void* const* d_in, const int* in_sizes, int n_in,
                              void* d_out, int out_size, void* d_ws, size_t ws_size,
                              hipStream_t stream)
{
    const void* x = d_in[0];
    char* ws = (char*)d_ws;
    const size_t N = NTOT;

    __bf16* h  = (__bf16*)ws;
    size_t off = N * 1024;
    __bf16* h1 = (__bf16*)(ws + off); off += N * 512;
    float* logit = (float*)(ws + off); off += N * 4;
    __bf16* wb = (__bf16*)(ws + off); off += 331008 * 2;
    int* flag = (int*)(ws + off); off += 16;
    float2* stats = (float2*)(ws + off); off += NAUDIO * sizeof(float2);
    float* partial = (float*)(ws + off); off += (size_t)NAUDIO * POOL_CHUNKS * 128 * 4;
    __bf16* g2 = h;                        // aliases dead h
    float* emb = (float*)(ws + N * 512);   // aliases dead h (2nd half)

    const int O_W1 = 0,      O_W2 = 262144, O_as1 = 327680, O_ad1 = 328192;
    const int O_b1 = 328704, O_as2 = 328960, O_ad2 = 329216, O_b2 = 329472;
    const int O_Wt = 329600, O_bt = 329728, O_Wa = 329736, O_ba = 329992;
    const int O_Wn = 330000, O_bn = 330896;

    W14 w;
    const void* srcs[14] = { d_in[4], d_in[8], d_in[5], d_in[6], d_in[7],
                             d_in[9], d_in[10], d_in[11], d_in[12], d_in[13],
                             d_in[14], d_in[15], d_in[16], d_in[17] };
    const int ns[14]   = { 262144, 65536, 512, 512, 256, 256, 256, 128,
                           128, 1, 256, 2, 896, 7 };
    const int offs[14] = { O_W1, O_W2, O_as1, O_ad1, O_b1, O_as2, O_ad2, O_b2,
                           O_Wt, O_bt, O_Wa, O_ba, O_Wn, O_bn };
    for (int i = 0; i < 14; i++) { w.s[i] = srcs[i]; w.n[i] = ns[i]; w.off[i] = offs[i]; }

    const int nwb = NTOT / 4;

    detect_dtype<<<1, 256, 0, stream>>>((const unsigned*)x, flag);
    convert_weights<<<512, 256, 0, stream>>>(w, flag, wb);

    // 1) h = x @ W1^T  (f32->bf16 conversion fused into A staging)
    gemm_tile<4, true><<<4 * (NTOT / 128), 256, 0, stream>>>(
        x, wb + O_W1, h, NTOT, 512, 512, flag);
    // 2) fused GAT layer 1: edge softmax + aggregate + relu -> h1
    agg_fused<256, true, false><<<nwb, 256, 0, stream>>>(
        h, wb + O_as1, wb + O_ad1, wb + O_b1, h1,
        nullptr, nullptr, nullptr, nullptr, nullptr, nullptr, flag);
    // 3) g2 = h1 @ W2^T
    gemm_tile<2, false><<<2 * (NTOT / 128), 256, 0, stream>>>(
        h1, wb + O_W2, g2, NTOT, 256, 256, flag);
    // 4) fused GAT layer 2 + node head: emb (f32) + node_pred + logit
    agg_fused<128, false, true><<<nwb, 256, 0, stream>>>(
        g2, wb + O_as2, wb + O_ad2, wb + O_b2, emb,
        wb + O_Wn, wb + O_bn, wb + O_Wt, wb + O_bt, d_out, logit, flag);
    // 5) per-audio softmax pool + audio head
    audio_stats<<<NAUDIO, 256, 0, stream>>>(logit, stats);
    audio_partial<<<NAUDIO * POOL_CHUNKS, 256, 0, stream>>>(emb, logit, stats, partial);
    audio_final<<<NAUDIO, 64, 0, stream>>>(partial, wb + O_Wa, wb + O_ba, d_out, flag);
}

// Round 6
// 698.211 us; speedup vs baseline: 1.2188x; 1.0135x over previous
//
#include <hip/hip_runtime.h>
#include <hip/hip_bf16.h>

typedef __bf16 bf16x8 __attribute__((ext_vector_type(8)));
typedef float f32x4 __attribute__((ext_vector_type(4)));

#define NTOT   131072
#define NODES_PER_AUDIO 2048
#define NAUDIO 64
#define BLKS_PER_AUDIO 512   // agg2 blocks per audio (4 nodes per block)

// ---------------------------------------------------------------------------
// dtype detection: flag = 1 -> bf16 inputs ; flag = 0 -> f32 inputs
// ---------------------------------------------------------------------------
__global__ __launch_bounds__(256)
void detect_dtype(const unsigned* __restrict__ x, int* __restrict__ flag)
{
    const int tid = threadIdx.x;
    int cnt = 0;
    for (int i = tid; i < 4096; i += 256) {
        unsigned e = (x[i] >> 7) & 0xFF;
        cnt += (e >= 100 && e <= 145) ? 1 : 0;
    }
    __shared__ int red[256];
    red[tid] = cnt; __syncthreads();
    for (int s = 128; s > 0; s >>= 1) {
        if (tid < s) red[tid] += red[tid + s];
        __syncthreads();
    }
    if (tid == 0) *flag = (red[0] > 3000) ? 1 : 0;
}

struct W14 { const void* s[14]; int n[14]; int off[14]; };

__global__ __launch_bounds__(256)
void convert_weights(W14 w, const int* __restrict__ flag, __bf16* __restrict__ wb)
{
    const int f = *flag;
    const int stride = gridDim.x * 256;
    for (int t = 0; t < 14; t++) {
        const void* src = w.s[t];
        __bf16* d = wb + w.off[t];
        for (int i = blockIdx.x * 256 + threadIdx.x; i < w.n[t]; i += stride)
            d[i] = f ? ((const __bf16*)src)[i] : (__bf16)((const float*)src)[i];
    }
}

// ---------------------------------------------------------------------------
// GEMM (EXACT round-0 structure, the measured-best): C = A @ W^T, 128x128
// tile, BK=64, 4 waves, mfma_f32_16x16x32_bf16, global_load_lds staging,
// single LDS buffer, 2 barriers/K-step, XCD-aware block swizzle.
// ---------------------------------------------------------------------------
template<int NX, bool DYN>
__global__ __launch_bounds__(256)
void gemm_tile(const void* __restrict__ Araw, const __bf16* __restrict__ W,
               __bf16* __restrict__ C, int M, int K, int Nc,
               const int* __restrict__ flagp)
{
    __shared__ __align__(16) __bf16 As[128 * 64];
    __shared__ __align__(16) __bf16 Bs[128 * 64];

    const int nb  = gridDim.x;
    const int ny  = nb / NX;
    const int ypx = ny >> 3;                 // y tiles per XCD
    const int bid = blockIdx.x;
    const int xcd = bid & 7;
    const int local = bid >> 3;
    const int by = xcd * ypx + local / NX;
    const int bx = local % NX;

    const int colBase = bx * 128;
    const int rowBase = by * 128;
    const int tid  = threadIdx.x;
    const int wave = tid >> 6;
    const int lane = tid & 63;
    const int wrow = (wave >> 1) * 64;
    const int wcol = (wave & 1) * 64;
    const int lr = lane & 15;
    const int lq = lane >> 4;
    int f = 1;
    if constexpr (DYN) f = *flagp;

    f32x4 acc[4][4] = {};

    const __bf16* A16 = (const __bf16*)Araw;
    const float*  A32 = (const float*)Araw;
    const __bf16* ap[4]; const float* af32[4]; const __bf16* bp[4];
    #pragma unroll
    for (int i = 0; i < 4; i++) {
        const int c = tid + 256 * i;
        const int r = c >> 3, q = c & 7;
        ap[i]   = A16 + (size_t)(rowBase + r) * K + q * 8;
        af32[i] = A32 + (size_t)(rowBase + r) * K + q * 8;
        bp[i]   = W   + (size_t)(colBase + r) * K + q * 8;
    }

    for (int k0 = 0; k0 < K; k0 += 64) {
        __syncthreads();
        #pragma unroll
        for (int i = 0; i < 4; i++) {
            const int c = tid + 256 * i;
            __builtin_amdgcn_global_load_lds(
                (const __attribute__((address_space(1))) void*)(bp[i] + k0),
                (__attribute__((address_space(3))) void*)&Bs[c * 8], 16, 0, 0);
        }
        if (!DYN || f) {
            #pragma unroll
            for (int i = 0; i < 4; i++) {
                const int c = tid + 256 * i;
                __builtin_amdgcn_global_load_lds(
                    (const __attribute__((address_space(1))) void*)(ap[i] + k0),
                    (__attribute__((address_space(3))) void*)&As[c * 8], 16, 0, 0);
            }
        } else {
            #pragma unroll
            for (int i = 0; i < 4; i++) {
                const int c = tid + 256 * i;
                float4 u0 = *(const float4*)(af32[i] + k0);
                float4 u1 = *(const float4*)(af32[i] + k0 + 4);
                __bf16 t[8] = {(__bf16)u0.x, (__bf16)u0.y, (__bf16)u0.z, (__bf16)u0.w,
                               (__bf16)u1.x, (__bf16)u1.y, (__bf16)u1.z, (__bf16)u1.w};
                *(int4*)&As[c * 8] = *(int4*)t;
            }
        }
        __syncthreads();

        #pragma unroll
        for (int kk = 0; kk < 2; kk++) {
            bf16x8 avf[4], bvf[4];
            #pragma unroll
            for (int i = 0; i < 4; i++)
                avf[i] = *(const bf16x8*)&As[(wrow + i * 16 + lr) * 64 + kk * 32 + lq * 8];
            #pragma unroll
            for (int j = 0; j < 4; j++)
                bvf[j] = *(const bf16x8*)&Bs[(wcol + j * 16 + lr) * 64 + kk * 32 + lq * 8];
            #pragma unroll
            for (int i = 0; i < 4; i++)
                #pragma unroll
                for (int j = 0; j < 4; j++)
                    acc[i][j] = __builtin_amdgcn_mfma_f32_16x16x32_bf16(
                        avf[i], bvf[j], acc[i][j], 0, 0, 0);
        }
    }

    #pragma unroll
    for (int i = 0; i < 4; i++) {
        #pragma unroll
        for (int j = 0; j < 4; j++) {
            int col = colBase + wcol + j * 16 + lr;
            #pragma unroll
            for (int r = 0; r < 4; r++) {
                int row = rowBase + wrow + i * 16 + lq * 4 + r;
                C[(size_t)row * Nc + col] = (__bf16)acc[i][j][r];
            }
        }
    }
}

// ---------------------------------------------------------------------------
// Fused GAT edge-softmax + aggregation.
// One wave per node n. In-edges = {self, n-1 if same audio}.
// FUSE_HEAD (layer 2): also computes node head (softmax7 -> node_pred),
// temporal logit, and ONLINE-SOFTMAX POOLING PARTIALS per block:
//   vbuf[blk][128] = sum_{n in blk} e^{lg_n - m_blk} * emb_n
//   msbuf[blk]     = (m_blk, s_blk = sum e^{lg_n - m_blk})
// -> emb and logit never hit HBM.
// ---------------------------------------------------------------------------
template<int C, bool RELU, bool FUSE_HEAD>
__global__ __launch_bounds__(256)
void agg_fused(const __bf16* __restrict__ h, const __bf16* __restrict__ a_s,
               const __bf16* __restrict__ a_d, const __bf16* __restrict__ bias,
               void* __restrict__ outv,
               const __bf16* __restrict__ Wn, const __bf16* __restrict__ bn,
               const __bf16* __restrict__ Wt, const __bf16* __restrict__ bt,
               void* __restrict__ node_pred, float* __restrict__ vbuf,
               float* __restrict__ msbuf, const int* __restrict__ flag)
{
    constexpr int D = 2 * C;
    constexpr int V = D / 64;
    const int blk = blockIdx.x;
    const int wave = threadIdx.x >> 6;
    const int n = blk * 4 + wave;
    const int lane = threadIdx.x & 63;
    const bool have_prev = (n & (NODES_PER_AUDIO - 1)) != 0;
    const size_t np = have_prev ? (size_t)(n - 1) : (size_t)n;
    const int base = lane * V;

    __bf16 h0v[V], h1v[V], asv[V], adv[V];
    if constexpr (V == 8) {
        *(int4*)h0v = *(const int4*)(h + (size_t)n * D + base);
        *(int4*)h1v = *(const int4*)(h + np * D + base);
        *(int4*)asv = *(const int4*)(a_s + base);
        *(int4*)adv = *(const int4*)(a_d + base);
    } else {
        *(int2*)h0v = *(const int2*)(h + (size_t)n * D + base);
        *(int2*)h1v = *(const int2*)(h + np * D + base);
        *(int2*)asv = *(const int2*)(a_s + base);
        *(int2*)adv = *(const int2*)(a_d + base);
    }

    float ps = 0.f, pd = 0.f, pp = 0.f;
    #pragma unroll
    for (int j = 0; j < V; j++) {
        float av = (float)asv[j], dv = (float)adv[j];
        float x0 = (float)h0v[j], x1 = (float)h1v[j];
        ps += x0 * av; pd += x0 * dv; pp += x1 * av;
    }
    #pragma unroll
    for (int off = 1; off < 32; off <<= 1) {
        ps += __shfl_xor(ps, off, 64);
        pd += __shfl_xor(pd, off, 64);
        pp += __shfl_xor(pp, off, 64);
    }

    float es = ps + pd;  es = es > 0.f ? es : 0.2f * es;
    float a_self = 1.f, a_prev = 0.f;
    if (have_prev) {
        float ep = pp + pd;  ep = ep > 0.f ? ep : 0.2f * ep;
        float m = fmaxf(es, ep);
        float wsx = __expf(es - m), wpx = __expf(ep - m);
        float inv = 1.f / (wsx + wpx);
        a_self = wsx * inv; a_prev = wpx * inv;
    }

    const int cb = (lane & 31) * V;
    float outj[V];
    #pragma unroll
    for (int j = 0; j < V; j++) {
        float p = a_self * (float)h0v[j] + a_prev * (float)h1v[j];
        p = 0.5f * (p + __shfl_xor(p, 32, 64));
        p += (float)bias[cb + j];
        if (RELU) p = fmaxf(p, 0.f);
        outj[j] = p;
    }

    if constexpr (!FUSE_HEAD) {
        if (lane < 32) {
            __bf16 ov[V];
            #pragma unroll
            for (int j = 0; j < V; j++) ov[j] = (__bf16)outj[j];
            if constexpr (V == 8)
                *(int4*)((__bf16*)outv + (size_t)n * C + cb) = *(int4*)ov;
            else
                *(int2*)((__bf16*)outv + (size_t)n * C + cb) = *(int2*)ov;
        }
    } else {
        __shared__ float psum[4][128];
        __shared__ float lgw[4];

        float acc[8];
        #pragma unroll
        for (int k = 0; k < 7; k++) {
            float a = 0.f;
            #pragma unroll
            for (int j = 0; j < V; j++)
                a += outj[j] * (float)Wn[k * C + cb + j];
            acc[k] = a;
        }
        {
            float a = 0.f;
            #pragma unroll
            for (int j = 0; j < V; j++)
                a += outj[j] * (float)Wt[cb + j];
            acc[7] = a;
        }
        #pragma unroll
        for (int off = 1; off < 32; off <<= 1)
            #pragma unroll
            for (int k = 0; k < 8; k++)
                acc[k] += __shfl_xor(acc[k], off, 64);

        if (lane == 0) {
            float lg[7], m = -1e30f;
            #pragma unroll
            for (int k = 0; k < 7; k++) {
                lg[k] = acc[k] + (float)bn[k];
                m = fmaxf(m, lg[k]);
            }
            float s = 0.f;
            #pragma unroll
            for (int k = 0; k < 7; k++) { lg[k] = __expf(lg[k] - m); s += lg[k]; }
            float inv = 1.f / s;
            if (*flag) {
                #pragma unroll
                for (int k = 0; k < 7; k++)
                    ((__bf16*)node_pred)[(size_t)n * 7 + k] = (__bf16)(lg[k] * inv);
            } else {
                #pragma unroll
                for (int k = 0; k < 7; k++)
                    ((float*)node_pred)[(size_t)n * 7 + k] = lg[k] * inv;
            }
            lgw[wave] = acc[7] + (float)bt[0];   // temporal logit of node n
        }
        __syncthreads();

        // block-local online-softmax partials over the 4 nodes
        const float m_b = fmaxf(fmaxf(lgw[0], lgw[1]), fmaxf(lgw[2], lgw[3]));
        if (lane < 32) {
            const float we = __expf(lgw[wave] - m_b);
            #pragma unroll
            for (int j = 0; j < V; j++)
                psum[wave][cb + j] = we * outj[j];
        }
        __syncthreads();

        const int tid = threadIdx.x;
        if (tid < 128) {
            vbuf[(size_t)blk * 128 + tid] =
                psum[0][tid] + psum[1][tid] + psum[2][tid] + psum[3][tid];
        } else if (tid == 128) {
            const float s_b = __expf(lgw[0] - m_b) + __expf(lgw[1] - m_b)
                            + __expf(lgw[2] - m_b) + __expf(lgw[3] - m_b);
            msbuf[(size_t)blk * 2]     = m_b;
            msbuf[(size_t)blk * 2 + 1] = s_b;
        }
    }
}

// ---------------------------------------------------------------------------
// Per-audio combine: M = max m_b ; S = sum e^{m_b-M} s_b ;
// attended[c] = sum e^{m_b-M} v_b[c] / S ; then audio head (Wa, ba).
// One block per audio.
// ---------------------------------------------------------------------------
__global__ __launch_bounds__(256)
void audio_comb(const float* __restrict__ vbuf, const float* __restrict__ msbuf,
                const __bf16* __restrict__ Wa, const __bf16* __restrict__ ba,
                void* __restrict__ outbase, const int* __restrict__ flag)
{
    const int b = blockIdx.x;
    const int tid = threadIdx.x;
    __shared__ float red[256];
    __shared__ float ew[BLKS_PER_AUDIO];
    __shared__ float att[128];
    const int base = b * BLKS_PER_AUDIO;

    // global max of block maxima
    float m = -1e30f;
    for (int k = tid; k < BLKS_PER_AUDIO; k += 256)
        m = fmaxf(m, msbuf[(size_t)(base + k) * 2]);
    red[tid] = m; __syncthreads();
    for (int s = 128; s > 0; s >>= 1) {
        if (tid < s) red[tid] = fmaxf(red[tid], red[tid + s]);
        __syncthreads();
    }
    m = red[0]; __syncthreads();

    // rescale factors + global sum
    float s = 0.f;
    for (int k = tid; k < BLKS_PER_AUDIO; k += 256) {
        const float e = __expf(msbuf[(size_t)(base + k) * 2] - m);
        ew[k] = e;
        s += e * msbuf[(size_t)(base + k) * 2 + 1];
    }
    red[tid] = s; __syncthreads();
    for (int st = 128; st > 0; st >>= 1) {
        if (tid < st) red[tid] += red[tid + st];
        __syncthreads();
    }
    const float invS = 1.f / red[0];
    __syncthreads();

    // attended: 256 threads = 2 halves over k, 128 channels
    const int c = tid & 127, half = tid >> 7;
    float a = 0.f;
    const int k0 = half * (BLKS_PER_AUDIO / 2);
    for (int k = k0; k < k0 + BLKS_PER_AUDIO / 2; ++k)
        a += ew[k] * vbuf[(size_t)(base + k) * 128 + c];
    red[tid] = a; __syncthreads();
    if (tid < 128) att[tid] = (red[tid] + red[tid + 128]) * invS;
    __syncthreads();

    // audio head on one wave
    if (tid < 64) {
        const int lane = tid;
        const float a0 = att[lane * 2], a1 = att[lane * 2 + 1];
        float p0 = a0 * (float)Wa[lane * 2]       + a1 * (float)Wa[lane * 2 + 1];
        float p1 = a0 * (float)Wa[128 + lane * 2] + a1 * (float)Wa[128 + lane * 2 + 1];
        #pragma unroll
        for (int off = 1; off < 64; off <<= 1) {
            p0 += __shfl_xor(p0, off, 64);
            p1 += __shfl_xor(p1, off, 64);
        }
        if (lane == 0) {
            const float r0 = p0 + (float)ba[0];
            const float r1 = p1 + (float)ba[1];
            if (*flag) {
                ((__bf16*)outbase)[(size_t)NTOT * 7 + b * 2 + 0] = (__bf16)r0;
                ((__bf16*)outbase)[(size_t)NTOT * 7 + b * 2 + 1] = (__bf16)r1;
            } else {
                ((float*)outbase)[(size_t)NTOT * 7 + b * 2 + 0] = r0;
                ((float*)outbase)[(size_t)NTOT * 7 + b * 2 + 1] = r1;
            }
        }
    }
}

// ---------------------------------------------------------------------------
extern "C" void kernel_launch(void* const* d_in, const int* in_sizes, int n_in,
                              void* d_out, int out_size, void* d_ws, size_t ws_size,
                              hipStream_t stream)
{
    const void* x = d_in[0];
    char* ws = (char*)d_ws;
    const size_t N = NTOT;

    __bf16* h  = (__bf16*)ws;
    size_t off = N * 1024;
    __bf16* h1 = (__bf16*)(ws + off); off += N * 512;
    __bf16* wb = (__bf16*)(ws + off); off += 331008 * 2;
    int* flag = (int*)(ws + off); off += 16;
    off = (off + 255) & ~(size_t)255;
    float* vbuf  = (float*)(ws + off); off += (size_t)(NTOT / 4) * 128 * 4;  // 16.8 MB
    float* msbuf = (float*)(ws + off); off += (size_t)(NTOT / 4) * 2 * 4;    // 0.26 MB
    __bf16* g2 = h;                        // aliases dead h

    const int O_W1 = 0,      O_W2 = 262144, O_as1 = 327680, O_ad1 = 328192;
    const int O_b1 = 328704, O_as2 = 328960, O_ad2 = 329216, O_b2 = 329472;
    const int O_Wt = 329600, O_bt = 329728, O_Wa = 329736, O_ba = 329992;
    const int O_Wn = 330000, O_bn = 330896;

    W14 w;
    const void* srcs[14] = { d_in[4], d_in[8], d_in[5], d_in[6], d_in[7],
                             d_in[9], d_in[10], d_in[11], d_in[12], d_in[13],
                             d_in[14], d_in[15], d_in[16], d_in[17] };
    const int ns[14]   = { 262144, 65536, 512, 512, 256, 256, 256, 128,
                           128, 1, 256, 2, 896, 7 };
    const int offs[14] = { O_W1, O_W2, O_as1, O_ad1, O_b1, O_as2, O_ad2, O_b2,
                           O_Wt, O_bt, O_Wa, O_ba, O_Wn, O_bn };
    for (int i = 0; i < 14; i++) { w.s[i] = srcs[i]; w.n[i] = ns[i]; w.off[i] = offs[i]; }

    const int nwb = NTOT / 4;

    detect_dtype<<<1, 256, 0, stream>>>((const unsigned*)x, flag);
    convert_weights<<<512, 256, 0, stream>>>(w, flag, wb);

    // 1) h = x @ W1^T  (f32->bf16 conversion fused into A staging)
    gemm_tile<4, true><<<4 * (NTOT / 128), 256, 0, stream>>>(
        x, wb + O_W1, h, NTOT, 512, 512, flag);
    // 2) fused GAT layer 1: edge softmax + aggregate + relu -> h1
    agg_fused<256, true, false><<<nwb, 256, 0, stream>>>(
        h, wb + O_as1, wb + O_ad1, wb + O_b1, h1,
        nullptr, nullptr, nullptr, nullptr, nullptr, nullptr, nullptr, flag);
    // 3) g2 = h1 @ W2^T
    gemm_tile<2, false><<<2 * (NTOT / 128), 256, 0, stream>>>(
        h1, wb + O_W2, g2, NTOT, 256, 256, flag);
    // 4) fused GAT layer 2 + node head + online-softmax pooling partials
    agg_fused<128, false, true><<<nwb, 256, 0, stream>>>(
        g2, wb + O_as2, wb + O_ad2, wb + O_b2, nullptr,
        wb + O_Wn, wb + O_bn, wb + O_Wt, wb + O_bt, d_out, vbuf, msbuf, flag);
    // 5) per-audio combine + audio head
    audio_comb<<<NAUDIO, 256, 0, stream>>>(vbuf, msbuf, wb + O_Wa, wb + O_ba,
                                           d_out, flag);
}